// Round 1
// baseline (765.479 us; speedup 1.0000x reference)
//
#include <hip/hip_runtime.h>
#include <stdint.h>

#define DIM 512
#define NHD 16
#define HD 32
#define NTOK 16384

typedef unsigned short u16;
typedef __attribute__((ext_vector_type(8))) short short8;  // 8 bf16 (4 VGPRs)
typedef __attribute__((ext_vector_type(4))) float f32x4;

__device__ __forceinline__ float bf2f(u16 u){ union{unsigned i; float f;} c; c.i=(unsigned)u<<16; return c.f; }
__device__ __forceinline__ float bflo(unsigned u){ union{unsigned i; float f;} c; c.i=u<<16; return c.f; }
__device__ __forceinline__ float bfhi(unsigned u){ union{unsigned i; float f;} c; c.i=u&0xffff0000u; return c.f; }
__device__ __forceinline__ u16 f2bf(float f){ union{float f; unsigned i;} c; c.f=f; unsigned r=(c.i + 0x7fffu + ((c.i>>16)&1u))>>16; return (u16)r; }

// window-order row -> token index (with optional shift roll-back/gather mapping)
// C=4,H=64,W=64, WC=2,WH=8,WW=8, shifts (1,4,4)
__device__ __forceinline__ int win_to_tok(int r, int shifted){
  int win = r >> 7, n = r & 127;
  int a = win >> 6, b = (win >> 3) & 7, c = win & 7;
  int ic = n >> 6, ih = (n >> 3) & 7, iw = n & 7;
  int gc = a*2 + ic, gh = b*8 + ih, gw = c*8 + iw;
  if (shifted){ gc = (gc + 1) & 3; gh = (gh + 4) & 63; gw = (gw + 4) & 63; }
  return (gc << 12) + (gh << 6) + gw;
}

// async global->LDS, 16B per lane (CK-style addrspace cast)
__device__ __forceinline__ void gload16(const void* g, void* l){
  __builtin_amdgcn_global_load_lds(
    (const __attribute__((address_space(1))) unsigned int*)(unsigned long long)g,
    (__attribute__((address_space(3))) unsigned int*)(unsigned int)(unsigned long long)l,
    16, 0, 0);
}

// ---------------- weight transpose + bf16 cast: W[K][N] -> Wt[N][K] ----------------
__global__ __launch_bounds__(256)
void transpose_kernel(const float* __restrict__ W, u16* __restrict__ Wt, int K, int N)
{
  __shared__ float t[32][33];
  int n0 = blockIdx.x*32, k0 = blockIdx.y*32;
  int tx = threadIdx.x & 31, ty = threadIdx.x >> 5;
  #pragma unroll
  for (int i=0;i<4;i++) t[ty + i*8][tx] = W[(size_t)(k0 + ty + i*8)*N + n0 + tx];
  __syncthreads();
  #pragma unroll
  for (int i=0;i<4;i++) Wt[(size_t)(n0 + ty + i*8)*K + k0 + tx] = f2bf(t[tx][ty + i*8]);
}

// ---------------- LayerNorm (+optional window gather w/ roll) -> bf16 ----------------
// mode: -1 identity row mapping, 0 window partition, 1 window partition + shift
__global__ __launch_bounds__(256)
void ln_kernel(const float* __restrict__ x, const float* __restrict__ g,
               const float* __restrict__ b, u16* __restrict__ out, int mode)
{
  int wave = threadIdx.x >> 6, lane = threadIdx.x & 63;
  int r = blockIdx.x * 4 + wave;
  int src = (mode < 0) ? r : win_to_tok(r, mode);
  const float4* xr = (const float4*)(x + (size_t)src * DIM);
  float4 v0 = xr[lane*2], v1 = xr[lane*2+1];
  float s  = v0.x+v0.y+v0.z+v0.w+v1.x+v1.y+v1.z+v1.w;
  float sq = v0.x*v0.x+v0.y*v0.y+v0.z*v0.z+v0.w*v0.w
           + v1.x*v1.x+v1.y*v1.y+v1.z*v1.z+v1.w*v1.w;
  #pragma unroll
  for (int o=32;o;o>>=1){ s += __shfl_xor(s,o); sq += __shfl_xor(sq,o); }
  float mean = s*(1.f/DIM);
  float var  = sq*(1.f/DIM) - mean*mean;
  float rstd = rsqrtf(var + 1e-5f);
  int c0 = lane*8;
  const float4* g4 = (const float4*)(g + c0);
  const float4* b4 = (const float4*)(b + c0);
  float4 ga = g4[0], gb = g4[1], ba = b4[0], bb = b4[1];
  float xv[8] = {v0.x,v0.y,v0.z,v0.w,v1.x,v1.y,v1.z,v1.w};
  float gg[8] = {ga.x,ga.y,ga.z,ga.w,gb.x,gb.y,gb.z,gb.w};
  float bv[8] = {ba.x,ba.y,ba.z,ba.w,bb.x,bb.y,bb.z,bb.w};
  union{u16 us[8]; uint4 u;} p;
  #pragma unroll
  for (int j=0;j<8;j++) p.us[j] = f2bf((xv[j]-mean)*rstd*gg[j] + bv[j]);
  ((uint4*)(out + (size_t)r*DIM))[lane] = p.u;
}

// ---------------- bf16 MFMA GEMM: out = X[M,K] @ Wt[N,K]^T + bias ----------------
// EPI 0: store bf16 (qkv)   EPI 1: scatter += into x residual (proj, win_rev+roll)
// EPI 2: gelu -> bf16 (fc1) EPI 3: += into x residual direct (fc2)
template<int EPI>
__global__ __launch_bounds__(256)
void gemm_kernel(const u16* __restrict__ X, const u16* __restrict__ Wt,
                 const float* __restrict__ bias, u16* __restrict__ obf,
                 float* __restrict__ xres, int M, int N, int K, int shifted)
{
  __shared__ u16 As[128*64];
  __shared__ u16 Bs[128*64];
  int tid = threadIdx.x, wave = tid>>6, lane = tid&63;
  int m0 = blockIdx.y*128, n0 = blockIdx.x*128;
  int wm = (wave>>1)*64, wn = (wave&1)*64;
  f32x4 acc[4][4] = {};
  int srow = tid>>3, soff = (tid&7)*8;   // 8 chunks of 16B per 128B row

  for (int k0=0; k0<K; k0+=64){
    __syncthreads();
    #pragma unroll
    for (int i=0;i<4;i++)
      gload16(X + (size_t)(m0 + i*32 + srow)*K + k0 + soff, (void*)(As + (i*256 + wave*64)*8));
    #pragma unroll
    for (int i=0;i<4;i++)
      gload16(Wt + (size_t)(n0 + i*32 + srow)*K + k0 + soff, (void*)(Bs + (i*256 + wave*64)*8));
    __syncthreads();
    #pragma unroll
    for (int kk=0; kk<64; kk+=32){
      short8 af[4], bfr[4];
      #pragma unroll
      for (int mi=0;mi<4;mi++)
        af[mi] = *(const short8*)(As + (wm + mi*16 + (lane&15))*64 + kk + (lane>>4)*8);
      #pragma unroll
      for (int nj=0;nj<4;nj++)
        bfr[nj] = *(const short8*)(Bs + (wn + nj*16 + (lane&15))*64 + kk + (lane>>4)*8);
      #pragma unroll
      for (int mi=0;mi<4;mi++)
        #pragma unroll
        for (int nj=0;nj<4;nj++)
          acc[mi][nj] = __builtin_amdgcn_mfma_f32_16x16x32_bf16(af[mi], bfr[nj], acc[mi][nj], 0,0,0);
    }
  }

  int lr = (lane>>4)*4, lc = lane&15;
  #pragma unroll
  for (int mi=0;mi<4;mi++){
    #pragma unroll
    for (int nj=0;nj<4;nj++){
      int col = n0 + wn + nj*16 + lc;
      float bv = bias[col];
      #pragma unroll
      for (int rr=0;rr<4;rr++){
        int row = m0 + wm + mi*16 + lr + rr;
        float v = acc[mi][nj][rr] + bv;
        if (EPI==0){
          obf[(size_t)row*N + col] = f2bf(v);
        } else if (EPI==1){
          int dst = win_to_tok(row, shifted);
          xres[(size_t)dst*DIM + col] += v;
        } else if (EPI==2){
          float t = 0.5f*v*(1.f + erff(v*0.70710678118654752f));
          obf[(size_t)row*N + col] = f2bf(t);
        } else {
          xres[(size_t)row*DIM + col] += v;
        }
      }
    }
  }
}

// ---------------- windowed attention, 1 block = (window, head), 1 thread = 1 q row ----------------
__global__ __launch_bounds__(128)
void attn_kernel(const u16* __restrict__ qkv, const float* __restrict__ btab,
                 u16* __restrict__ out, int shifted)
{
  __shared__ u16 Ks[128*32];
  __shared__ u16 Vs[128*32];
  __shared__ float biasl[675];
  __shared__ int rid[128];
  int win = blockIdx.x >> 4, h = blockIdx.x & 15;
  int tid = threadIdx.x;
  size_t base = (size_t)win*128*1536 + (size_t)h*32;

  #pragma unroll
  for (int p=0;p<4;p++){
    int m = p*32 + (tid>>2), part = tid&3;
    *(uint4*)(Ks + m*32 + part*8) = *(const uint4*)(qkv + base + (size_t)m*1536 + 512  + part*8);
    *(uint4*)(Vs + m*32 + part*8) = *(const uint4*)(qkv + base + (size_t)m*1536 + 1024 + part*8);
  }
  for (int e=tid; e<675; e+=128) biasl[e] = btab[e*16 + h];

  int ic = tid>>6, ih=(tid>>3)&7, iw=tid&7;
  if (shifted){
    int a=win>>6, b=(win>>3)&7, c=win&7;
    int gc=a*2+ic, gh=b*8+ih, gw=c*8+iw;
    int rc = (gc<2)?0:((gc<3)?1:2);
    int rh = (gh<56)?0:((gh<60)?1:2);
    int rw = (gw<56)?0:((gw<60)?1:2);
    rid[tid] = rc*9 + rh*3 + rw;
  }
  __syncthreads();

  // load q row, pre-scaled
  float q[32];
  const u16* qp = qkv + base + (size_t)tid*1536;
  {
    const uint4* q4 = (const uint4*)qp;
    #pragma unroll
    for (int p=0;p<4;p++){
      uint4 u = q4[p];
      unsigned w[4] = {u.x,u.y,u.z,u.w};
      #pragma unroll
      for (int j=0;j<4;j++){
        q[p*8 + j*2    ] = bflo(w[j]) * 0.17677669529663687f;
        q[p*8 + j*2 + 1] = bfhi(w[j]) * 0.17677669529663687f;
      }
    }
  }

  float m_run = -1e30f, l_run = 0.f;
  float acc[32];
  #pragma unroll
  for (int d=0;d<32;d++) acc[d]=0.f;
  int myrid = shifted ? rid[tid] : 0;

  for (int m=0;m<128;m++){
    int jc=m>>6, jh=(m>>3)&7, jw=m&7;
    int idx = (ic-jc+1)*225 + (ih-jh+7)*15 + (iw-jw+7);
    float s = biasl[idx];
    if (shifted && rid[m]!=myrid) s -= 100.f;
    const unsigned* kr = (const unsigned*)(Ks + m*32);
    float dot = 0.f;
    #pragma unroll
    for (int dd=0; dd<16; dd++){
      unsigned u = kr[dd];
      dot += q[2*dd]*bflo(u) + q[2*dd+1]*bfhi(u);
    }
    s += dot;
    float mn = fmaxf(m_run, s);
    float corr = __expf(m_run - mn);
    float p = __expf(s - mn);
    l_run = l_run*corr + p;
    const unsigned* vr = (const unsigned*)(Vs + m*32);
    #pragma unroll
    for (int dd=0; dd<16; dd++){
      unsigned u = vr[dd];
      acc[2*dd]   = acc[2*dd]  *corr + p*bflo(u);
      acc[2*dd+1] = acc[2*dd+1]*corr + p*bfhi(u);
    }
    m_run = mn;
  }
  float inv = 1.f/l_run;
  union{u16 us[32]; uint4 u[4];} pk;
  #pragma unroll
  for (int d=0;d<32;d++) pk.us[d] = f2bf(acc[d]*inv);
  uint4* op = (uint4*)(out + (size_t)(win*128 + tid)*DIM + (size_t)h*32);
  #pragma unroll
  for (int p=0;p<4;p++) op[p] = pk.u[p];
}

// ---------------- host launcher ----------------
extern "C" void kernel_launch(void* const* d_in, const int* in_sizes, int n_in,
                              void* d_out, int out_size, void* d_ws, size_t ws_size,
                              hipStream_t stream)
{
  const float* x_in   = (const float*)d_in[0];
  const float* ln1_g  = (const float*)d_in[1];
  const float* ln1_b  = (const float*)d_in[2];
  const float* qkv_w  = (const float*)d_in[3];
  const float* qkv_b  = (const float*)d_in[4];
  const float* btab   = (const float*)d_in[5];
  const float* proj_w = (const float*)d_in[6];
  const float* proj_b = (const float*)d_in[7];
  const float* ln2_g  = (const float*)d_in[8];
  const float* ln2_b  = (const float*)d_in[9];
  const float* fc1_w  = (const float*)d_in[10];
  const float* fc1_b  = (const float*)d_in[11];
  const float* fc2_w  = (const float*)d_in[12];
  const float* fc2_b  = (const float*)d_in[13];

  char* ws = (char*)d_ws;
  size_t off = 0;
  auto alloc = [&](size_t bytes)->char*{ char* p = ws + off; off += (bytes + 255) & ~(size_t)255; return p; };
  u16* wT_qkv = (u16*)alloc((size_t)2*512*1536*2);
  u16* wT_proj= (u16*)alloc((size_t)2*512*512*2);
  u16* wT_fc1 = (u16*)alloc((size_t)2*2048*512*2);
  u16* wT_fc2 = (u16*)alloc((size_t)2*512*2048*2);
  u16* bufA   = (u16*)alloc((size_t)16384*2048*2);  // xw (first 1/4) then fc1 act
  u16* bufQ   = (u16*)alloc((size_t)16384*1536*2);  // qkv
  u16* bufB   = (u16*)alloc((size_t)16384*512*2);   // attn out / ln2 out
  (void)ws_size; (void)in_sizes; (void)n_in; (void)out_size;

  float* x = (float*)d_out;   // residual stream lives in d_out
  hipMemcpyAsync(x, x_in, (size_t)NTOK*DIM*4, hipMemcpyDeviceToDevice, stream);

  for (int i=0;i<2;i++){
    transpose_kernel<<<dim3(1536/32, 512/32), 256, 0, stream>>>(qkv_w + (size_t)i*512*1536, wT_qkv + (size_t)i*512*1536, 512, 1536);
    transpose_kernel<<<dim3( 512/32, 512/32), 256, 0, stream>>>(proj_w + (size_t)i*512*512,  wT_proj + (size_t)i*512*512,  512, 512);
    transpose_kernel<<<dim3(2048/32, 512/32), 256, 0, stream>>>(fc1_w + (size_t)i*512*2048, wT_fc1 + (size_t)i*2048*512, 512, 2048);
    transpose_kernel<<<dim3( 512/32,2048/32), 256, 0, stream>>>(fc2_w + (size_t)i*2048*512, wT_fc2 + (size_t)i*512*2048, 2048, 512);
  }

  for (int i=0;i<2;i++){
    ln_kernel<<<4096, 256, 0, stream>>>(x, ln1_g+i*512, ln1_b+i*512, bufA, i);
    gemm_kernel<0><<<dim3(12,128), 256, 0, stream>>>(bufA, wT_qkv+(size_t)i*512*1536, qkv_b+i*1536, bufQ, nullptr, NTOK,1536,512, 0);
    attn_kernel<<<2048, 128, 0, stream>>>(bufQ, btab + (size_t)i*675*16, bufB, i);
    gemm_kernel<1><<<dim3(4,128), 256, 0, stream>>>(bufB, wT_proj+(size_t)i*512*512, proj_b+i*512, nullptr, x, NTOK,512,512, i);
    ln_kernel<<<4096, 256, 0, stream>>>(x, ln2_g+i*512, ln2_b+i*512, bufB, -1);
    gemm_kernel<2><<<dim3(16,128), 256, 0, stream>>>(bufB, wT_fc1+(size_t)i*2048*512, fc1_b+i*2048, bufA, nullptr, NTOK,2048,512, 0);
    gemm_kernel<3><<<dim3(4,128), 256, 0, stream>>>(bufA, wT_fc2+(size_t)i*512*2048, fc2_b+i*512, nullptr, x, NTOK,512,2048, 0);
  }
}

// Round 3
// 531.016 us; speedup vs baseline: 1.4415x; 1.4415x over previous
//
#include <hip/hip_runtime.h>
#include <stdint.h>

#define DIM 512
#define NHD 16
#define HD 32
#define NTOK 16384

typedef unsigned short u16;
typedef __attribute__((ext_vector_type(8))) short short8;  // 8 bf16 (4 VGPRs)
typedef __attribute__((ext_vector_type(4))) float f32x4;

__device__ __forceinline__ float bf2f(u16 u){ union{unsigned i; float f;} c; c.i=(unsigned)u<<16; return c.f; }
__device__ __forceinline__ float bflo(unsigned u){ union{unsigned i; float f;} c; c.i=u<<16; return c.f; }
__device__ __forceinline__ float bfhi(unsigned u){ union{unsigned i; float f;} c; c.i=u&0xffff0000u; return c.f; }
__device__ __forceinline__ u16 f2bf(float f){ union{float f; unsigned i;} c; c.f=f; unsigned r=(c.i + 0x7fffu + ((c.i>>16)&1u))>>16; return (u16)r; }

// window-order row -> token index (with optional shift roll-back/gather mapping)
__device__ __forceinline__ int win_to_tok(int r, int shifted){
  int win = r >> 7, n = r & 127;
  int a = win >> 6, b = (win >> 3) & 7, c = win & 7;
  int ic = n >> 6, ih = (n >> 3) & 7, iw = n & 7;
  int gc = a*2 + ic, gh = b*8 + ih, gw = c*8 + iw;
  if (shifted){ gc = (gc + 1) & 3; gh = (gh + 4) & 63; gw = (gw + 4) & 63; }
  return (gc << 12) + (gh << 6) + gw;
}

__device__ __forceinline__ void gload16(const void* g, void* l){
  __builtin_amdgcn_global_load_lds(
    (const __attribute__((address_space(1))) unsigned int*)(unsigned long long)g,
    (__attribute__((address_space(3))) unsigned int*)(unsigned int)(unsigned long long)l,
    16, 0, 0);
}

// ---------------- weight transpose + bf16 cast ----------------
__global__ __launch_bounds__(256)
void transpose_kernel(const float* __restrict__ W, u16* __restrict__ Wt, int K, int N)
{
  __shared__ float t[32][33];
  int n0 = blockIdx.x*32, k0 = blockIdx.y*32;
  int tx = threadIdx.x & 31, ty = threadIdx.x >> 5;
  #pragma unroll
  for (int i=0;i<4;i++) t[ty + i*8][tx] = W[(size_t)(k0 + ty + i*8)*N + n0 + tx];
  __syncthreads();
  #pragma unroll
  for (int i=0;i<4;i++) Wt[(size_t)(n0 + ty + i*8)*K + k0 + tx] = f2bf(t[tx][ty + i*8]);
}

// ---------------- LayerNorm (+optional window gather w/ roll) -> bf16 ----------------
__global__ __launch_bounds__(256)
void ln_kernel(const float* __restrict__ x, const float* __restrict__ g,
               const float* __restrict__ b, u16* __restrict__ out, int mode)
{
  int wave = threadIdx.x >> 6, lane = threadIdx.x & 63;
  int r = blockIdx.x * 4 + wave;
  int src = (mode < 0) ? r : win_to_tok(r, mode);
  const float4* xr = (const float4*)(x + (size_t)src * DIM);
  float4 v0 = xr[lane*2], v1 = xr[lane*2+1];
  float s  = v0.x+v0.y+v0.z+v0.w+v1.x+v1.y+v1.z+v1.w;
  float sq = v0.x*v0.x+v0.y*v0.y+v0.z*v0.z+v0.w*v0.w
           + v1.x*v1.x+v1.y*v1.y+v1.z*v1.z+v1.w*v1.w;
  #pragma unroll
  for (int o=32;o;o>>=1){ s += __shfl_xor(s,o); sq += __shfl_xor(sq,o); }
  float mean = s*(1.f/DIM);
  float var  = sq*(1.f/DIM) - mean*mean;
  float rstd = rsqrtf(var + 1e-5f);
  int c0 = lane*8;
  const float4* g4 = (const float4*)(g + c0);
  const float4* b4 = (const float4*)(b + c0);
  float4 ga = g4[0], gb = g4[1], ba = b4[0], bb = b4[1];
  float xv[8] = {v0.x,v0.y,v0.z,v0.w,v1.x,v1.y,v1.z,v1.w};
  float gg[8] = {ga.x,ga.y,ga.z,ga.w,gb.x,gb.y,gb.z,gb.w};
  float bv[8] = {ba.x,ba.y,ba.z,ba.w,bb.x,bb.y,bb.z,bb.w};
  union{u16 us[8]; uint4 u;} p;
  #pragma unroll
  for (int j=0;j<8;j++) p.us[j] = f2bf((xv[j]-mean)*rstd*gg[j] + bv[j]);
  ((uint4*)(out + (size_t)r*DIM))[lane] = p.u;
}

// ---------------- bf16 MFMA GEMM ----------------
template<int EPI>
__global__ __launch_bounds__(256)
void gemm_kernel(const u16* __restrict__ X, const u16* __restrict__ Wt,
                 const float* __restrict__ bias, u16* __restrict__ obf,
                 float* __restrict__ xres, int M, int N, int K, int shifted)
{
  __shared__ u16 As[128*64];
  __shared__ u16 Bs[128*64];
  int tid = threadIdx.x, wave = tid>>6, lane = tid&63;
  int m0 = blockIdx.y*128, n0 = blockIdx.x*128;
  int wm = (wave>>1)*64, wn = (wave&1)*64;
  f32x4 acc[4][4] = {};
  int srow = tid>>3, soff = (tid&7)*8;

  for (int k0=0; k0<K; k0+=64){
    __syncthreads();
    #pragma unroll
    for (int i=0;i<4;i++)
      gload16(X + (size_t)(m0 + i*32 + srow)*K + k0 + soff, (void*)(As + (i*256 + wave*64)*8));
    #pragma unroll
    for (int i=0;i<4;i++)
      gload16(Wt + (size_t)(n0 + i*32 + srow)*K + k0 + soff, (void*)(Bs + (i*256 + wave*64)*8));
    __syncthreads();
    #pragma unroll
    for (int kk=0; kk<64; kk+=32){
      short8 af[4], bfr[4];
      #pragma unroll
      for (int mi=0;mi<4;mi++)
        af[mi] = *(const short8*)(As + (wm + mi*16 + (lane&15))*64 + kk + (lane>>4)*8);
      #pragma unroll
      for (int nj=0;nj<4;nj++)
        bfr[nj] = *(const short8*)(Bs + (wn + nj*16 + (lane&15))*64 + kk + (lane>>4)*8);
      #pragma unroll
      for (int mi=0;mi<4;mi++)
        #pragma unroll
        for (int nj=0;nj<4;nj++)
          acc[mi][nj] = __builtin_amdgcn_mfma_f32_16x16x32_bf16(af[mi], bfr[nj], acc[mi][nj], 0,0,0);
    }
  }

  int lr = (lane>>4)*4, lc = lane&15;
  #pragma unroll
  for (int mi=0;mi<4;mi++){
    #pragma unroll
    for (int nj=0;nj<4;nj++){
      int col = n0 + wn + nj*16 + lc;
      float bv = bias[col];
      #pragma unroll
      for (int rr=0;rr<4;rr++){
        int row = m0 + wm + mi*16 + lr + rr;
        float v = acc[mi][nj][rr] + bv;
        if (EPI==0){
          obf[(size_t)row*N + col] = f2bf(v);
        } else if (EPI==1){
          int dst = win_to_tok(row, shifted);
          xres[(size_t)dst*DIM + col] += v;
        } else if (EPI==2){
          float t = 0.5f*v*(1.f + erff(v*0.70710678118654752f));
          obf[(size_t)row*N + col] = f2bf(t);
        } else {
          xres[(size_t)row*DIM + col] += v;
        }
      }
    }
  }
}

// ---------------- rel-pos bias expansion: biasM[h][q][k] ----------------
__global__ __launch_bounds__(256)
void bias_kernel(const float* __restrict__ btab, float* __restrict__ biasM)
{
  int gid = blockIdx.x*256 + threadIdx.x;   // 16*128*128
  int q = (gid >> 7) & 127, k = gid & 127, h = gid >> 14;
  int ic=q>>6, ih=(q>>3)&7, iw=q&7, jc=k>>6, jh=(k>>3)&7, jw=k&7;
  int idx = (ic-jc+1)*225 + (ih-jh+7)*15 + (iw-jw+7);
  biasM[gid] = btab[idx*16 + h];
}

// ---------------- MFMA windowed attention ----------------
// block = (window, head): 4 waves, wave w owns q-rows [w*32, w*32+32)
__global__ __launch_bounds__(256)
void attn_kernel(const u16* __restrict__ qkv, const float* __restrict__ biasM,
                 u16* __restrict__ out, int shifted)
{
  __shared__ u16 Ks[128*32];    // [krow][d], 16B-chunk ^= (krow&3)<<4
  __shared__ u16 VsT[32*128];   // [d][krow], byte ^= (d&7)<<4
  __shared__ u16 Ps[4][32*128]; // per-wave [q][k], byte ^= (q&7)<<4
  __shared__ int rid[128];
  int win = blockIdx.x >> 4, h = blockIdx.x & 15;
  int tid = threadIdx.x, wave = tid>>6, lane = tid&63;
  size_t base = (size_t)win*128*1536 + (size_t)h*32;

  { // stage K (swizzled) and V transposed (swizzled)
    int m = tid>>1, half = tid&1;
    const uint4* ks = (const uint4*)(qkv + base + (size_t)m*1536 + 512 + half*16);
    uint4 k0v = ks[0], k1v = ks[1];
    char* krow = (char*)Ks + m*64;
    int c0 = half*32, sw = (m&3)<<4;
    *(uint4*)(krow + ((c0     ) ^ sw)) = k0v;
    *(uint4*)(krow + ((c0 + 16) ^ sw)) = k1v;
    const uint4* vs = (const uint4*)(qkv + base + (size_t)m*1536 + 1024 + half*16);
    union{u16 us[16]; uint4 u[2];} vv; vv.u[0]=vs[0]; vv.u[1]=vs[1];
    #pragma unroll
    for (int j=0;j<16;j++){
      int d = half*16 + j;
      *(u16*)((char*)VsT + ((d*256 + m*2) ^ ((d&7)<<4))) = vv.us[j];
    }
  }
  if (shifted && tid < 128){
    int a=win>>6, b=(win>>3)&7, c=win&7;
    int gc=a*2+(tid>>6), gh=b*8+((tid>>3)&7), gw=c*8+(tid&7);
    int rc = (gc<2)?0:((gc<3)?1:2);
    int rh = (gh<56)?0:((gh<60)?1:2);
    int rw = (gw<56)?0:((gw<60)?1:2);
    rid[tid] = rc*9 + rh*3 + rw;
  }
  __syncthreads();

  int q0 = wave*32;
  // ---- QK^T: S[32x128] ----
  short8 qf[2];
  #pragma unroll
  for (int mi=0;mi<2;mi++){
    int ql = 16*mi + (lane&15);
    qf[mi] = *(const short8*)(qkv + base + (size_t)(q0+ql)*1536 + (lane>>4)*8);
  }
  f32x4 s[2][8] = {};
  #pragma unroll
  for (int nj=0;nj<8;nj++){
    int row = (lane&15) + 16*nj;
    short8 kf = *(const short8*)((char*)Ks + row*64 + ((((lane>>4)<<4)) ^ ((row&3)<<4)));
    #pragma unroll
    for (int mi=0;mi<2;mi++)
      s[mi][nj] = __builtin_amdgcn_mfma_f32_16x16x32_bf16(qf[mi], kf, s[mi][nj], 0,0,0);
  }

  // ---- softmax (bias + mask), write P (bf16) to per-wave LDS ----
  int rk[8];
  if (shifted){
    #pragma unroll
    for (int nj=0;nj<8;nj++) rk[nj] = rid[(lane&15) + 16*nj];
  }
  float invl[2][4];
  char* pbase = (char*)Ps[wave];
  #pragma unroll
  for (int mi=0;mi<2;mi++){
    #pragma unroll
    for (int r=0;r<4;r++){
      int ql = 16*mi + ((lane>>4)<<2) + r;
      int qw = q0 + ql;
      const float* bp = biasM + (((h<<7) + qw)<<7) + (lane&15);
      int rq = shifted ? rid[qw] : 0;
      float sv[8]; float mx = -1e30f;
      #pragma unroll
      for (int nj=0;nj<8;nj++){
        float v = s[mi][nj][r] * 0.17677669529663687f + bp[nj*16];
        if (shifted && rk[nj] != rq) v -= 100.f;
        sv[nj] = v; mx = fmaxf(mx, v);
      }
      #pragma unroll
      for (int o=1;o<16;o<<=1) mx = fmaxf(mx, __shfl_xor(mx, o));
      float sum = 0.f;
      #pragma unroll
      for (int nj=0;nj<8;nj++){ float p = __expf(sv[nj]-mx); sv[nj]=p; sum += p; }
      #pragma unroll
      for (int o=1;o<16;o<<=1) sum += __shfl_xor(sum, o);
      invl[mi][r] = 1.f/sum;
      char* prow = pbase + ql*256;
      int sw = (ql&7)<<4;
      #pragma unroll
      for (int nj=0;nj<8;nj++)
        *(u16*)(prow + ((((lane&15) + (nj<<4))<<1) ^ sw)) = f2bf(sv[nj]);
    }
  }

  // ---- PV: O[32x32] ----
  f32x4 o2[2][2] = {};
  #pragma unroll
  for (int kk=0;kk<4;kk++){
    int coff = kk*64 + ((lane>>4)<<4);
    short8 pa[2], vb[2];
    #pragma unroll
    for (int mi=0;mi<2;mi++){
      int ql = 16*mi + (lane&15);
      pa[mi] = *(const short8*)(pbase + ql*256 + (coff ^ ((ql&7)<<4)));
    }
    #pragma unroll
    for (int nj=0;nj<2;nj++){
      int d = (lane&15) + 16*nj;
      vb[nj] = *(const short8*)((char*)VsT + d*256 + (coff ^ ((d&7)<<4)));
    }
    #pragma unroll
    for (int mi=0;mi<2;mi++)
      #pragma unroll
      for (int nj=0;nj<2;nj++)
        o2[mi][nj] = __builtin_amdgcn_mfma_f32_16x16x32_bf16(pa[mi], vb[nj], o2[mi][nj], 0,0,0);
  }

  // ---- epilogue: scale by 1/l, store bf16 ----
  #pragma unroll
  for (int mi=0;mi<2;mi++){
    #pragma unroll
    for (int nj=0;nj<2;nj++){
      #pragma unroll
      for (int r=0;r<4;r++){
        int ql = 16*mi + ((lane>>4)<<2) + r;
        int d  = (lane&15) + (nj<<4);
        out[(size_t)(win*128 + q0 + ql)*DIM + (h<<5) + d] = f2bf(o2[mi][nj][r] * invl[mi][r]);
      }
    }
  }
}

// ---------------- host launcher ----------------
extern "C" void kernel_launch(void* const* d_in, const int* in_sizes, int n_in,
                              void* d_out, int out_size, void* d_ws, size_t ws_size,
                              hipStream_t stream)
{
  const float* x_in   = (const float*)d_in[0];
  const float* ln1_g  = (const float*)d_in[1];
  const float* ln1_b  = (const float*)d_in[2];
  const float* qkv_w  = (const float*)d_in[3];
  const float* qkv_b  = (const float*)d_in[4];
  const float* btab   = (const float*)d_in[5];
  const float* proj_w = (const float*)d_in[6];
  const float* proj_b = (const float*)d_in[7];
  const float* ln2_g  = (const float*)d_in[8];
  const float* ln2_b  = (const float*)d_in[9];
  const float* fc1_w  = (const float*)d_in[10];
  const float* fc1_b  = (const float*)d_in[11];
  const float* fc2_w  = (const float*)d_in[12];
  const float* fc2_b  = (const float*)d_in[13];

  char* ws = (char*)d_ws;
  size_t off = 0;
  auto alloc = [&](size_t bytes)->char*{ char* p = ws + off; off += (bytes + 255) & ~(size_t)255; return p; };
  u16* wT_qkv = (u16*)alloc((size_t)2*512*1536*2);
  u16* wT_proj= (u16*)alloc((size_t)2*512*512*2);
  u16* wT_fc1 = (u16*)alloc((size_t)2*2048*512*2);
  u16* wT_fc2 = (u16*)alloc((size_t)2*512*2048*2);
  u16* bufA   = (u16*)alloc((size_t)16384*2048*2);
  u16* bufQ   = (u16*)alloc((size_t)16384*1536*2);
  u16* bufB   = (u16*)alloc((size_t)16384*512*2);
  float* biasM= (float*)alloc((size_t)16*128*128*4);
  (void)ws_size; (void)in_sizes; (void)n_in; (void)out_size;

  float* x = (float*)d_out;
  hipMemcpyAsync(x, x_in, (size_t)NTOK*DIM*4, hipMemcpyDeviceToDevice, stream);

  for (int i=0;i<2;i++){
    transpose_kernel<<<dim3(1536/32, 512/32), 256, 0, stream>>>(qkv_w + (size_t)i*512*1536, wT_qkv + (size_t)i*512*1536, 512, 1536);
    transpose_kernel<<<dim3( 512/32, 512/32), 256, 0, stream>>>(proj_w + (size_t)i*512*512,  wT_proj + (size_t)i*512*512,  512, 512);
    transpose_kernel<<<dim3(2048/32, 512/32), 256, 0, stream>>>(fc1_w + (size_t)i*512*2048, wT_fc1 + (size_t)i*2048*512, 512, 2048);
    transpose_kernel<<<dim3( 512/32,2048/32), 256, 0, stream>>>(fc2_w + (size_t)i*2048*512, wT_fc2 + (size_t)i*512*2048, 2048, 512);
  }

  for (int i=0;i<2;i++){
    ln_kernel<<<4096, 256, 0, stream>>>(x, ln1_g+i*512, ln1_b+i*512, bufA, i);
    gemm_kernel<0><<<dim3(12,128), 256, 0, stream>>>(bufA, wT_qkv+(size_t)i*512*1536, qkv_b+i*1536, bufQ, nullptr, NTOK,1536,512, 0);
    bias_kernel<<<1024, 256, 0, stream>>>(btab + (size_t)i*675*16, biasM);
    attn_kernel<<<2048, 256, 0, stream>>>(bufQ, biasM, bufB, i);
    gemm_kernel<1><<<dim3(4,128), 256, 0, stream>>>(bufB, wT_proj+(size_t)i*512*512, proj_b+i*512, nullptr, x, NTOK,512,512, i);
    ln_kernel<<<4096, 256, 0, stream>>>(x, ln2_g+i*512, ln2_b+i*512, bufB, -1);
    gemm_kernel<2><<<dim3(16,128), 256, 0, stream>>>(bufB, wT_fc1+(size_t)i*2048*512, fc1_b+i*2048, bufA, nullptr, NTOK,2048,512, 0);
    gemm_kernel<3><<<dim3(4,128), 256, 0, stream>>>(bufA, wT_fc2+(size_t)i*512*2048, fc2_b+i*512, nullptr, x, NTOK,512,2048, 0);
  }
}

// Round 4
// 461.365 us; speedup vs baseline: 1.6592x; 1.1510x over previous
//
#include <hip/hip_runtime.h>
#include <stdint.h>

#define DIM 512
#define NHD 16
#define HD 32
#define NTOK 16384

typedef unsigned short u16;
typedef __attribute__((ext_vector_type(8))) short short8;  // 8 bf16 (4 VGPRs)
typedef __attribute__((ext_vector_type(4))) float f32x4;

__device__ __forceinline__ float bf2f(u16 u){ union{unsigned i; float f;} c; c.i=(unsigned)u<<16; return c.f; }
__device__ __forceinline__ float bflo(unsigned u){ union{unsigned i; float f;} c; c.i=u<<16; return c.f; }
__device__ __forceinline__ float bfhi(unsigned u){ union{unsigned i; float f;} c; c.i=u&0xffff0000u; return c.f; }
__device__ __forceinline__ u16 f2bf(float f){ union{float f; unsigned i;} c; c.f=f; unsigned r=(c.i + 0x7fffu + ((c.i>>16)&1u))>>16; return (u16)r; }

// window-order row -> token index (with optional shift roll-back/gather mapping)
__device__ __forceinline__ int win_to_tok(int r, int shifted){
  int win = r >> 7, n = r & 127;
  int a = win >> 6, b = (win >> 3) & 7, c = win & 7;
  int ic = n >> 6, ih = (n >> 3) & 7, iw = n & 7;
  int gc = a*2 + ic, gh = b*8 + ih, gw = c*8 + iw;
  if (shifted){ gc = (gc + 1) & 3; gh = (gh + 4) & 63; gw = (gw + 4) & 63; }
  return (gc << 12) + (gh << 6) + gw;
}

__device__ __forceinline__ void gload16(const void* g, void* l){
  __builtin_amdgcn_global_load_lds(
    (const __attribute__((address_space(1))) unsigned int*)(unsigned long long)g,
    (__attribute__((address_space(3))) unsigned int*)(unsigned int)(unsigned long long)l,
    16, 0, 0);
}

// ---------------- weight transpose + bf16 cast ----------------
__global__ __launch_bounds__(256)
void transpose_kernel(const float* __restrict__ W, u16* __restrict__ Wt, int K, int N)
{
  __shared__ float t[32][33];
  int n0 = blockIdx.x*32, k0 = blockIdx.y*32;
  int tx = threadIdx.x & 31, ty = threadIdx.x >> 5;
  #pragma unroll
  for (int i=0;i<4;i++) t[ty + i*8][tx] = W[(size_t)(k0 + ty + i*8)*N + n0 + tx];
  __syncthreads();
  #pragma unroll
  for (int i=0;i<4;i++) Wt[(size_t)(n0 + ty + i*8)*K + k0 + tx] = f2bf(t[tx][ty + i*8]);
}

// ---------------- LayerNorm (+optional window gather w/ roll) -> bf16 ----------------
__global__ __launch_bounds__(256)
void ln_kernel(const float* __restrict__ x, const float* __restrict__ g,
               const float* __restrict__ b, u16* __restrict__ out, int mode)
{
  int wave = threadIdx.x >> 6, lane = threadIdx.x & 63;
  int r = blockIdx.x * 4 + wave;
  int src = (mode < 0) ? r : win_to_tok(r, mode);
  const float4* xr = (const float4*)(x + (size_t)src * DIM);
  float4 v0 = xr[lane*2], v1 = xr[lane*2+1];
  float s  = v0.x+v0.y+v0.z+v0.w+v1.x+v1.y+v1.z+v1.w;
  float sq = v0.x*v0.x+v0.y*v0.y+v0.z*v0.z+v0.w*v0.w
           + v1.x*v1.x+v1.y*v1.y+v1.z*v1.z+v1.w*v1.w;
  #pragma unroll
  for (int o=32;o;o>>=1){ s += __shfl_xor(s,o); sq += __shfl_xor(sq,o); }
  float mean = s*(1.f/DIM);
  float var  = sq*(1.f/DIM) - mean*mean;
  float rstd = rsqrtf(var + 1e-5f);
  int c0 = lane*8;
  const float4* g4 = (const float4*)(g + c0);
  const float4* b4 = (const float4*)(b + c0);
  float4 ga = g4[0], gb = g4[1], ba = b4[0], bb = b4[1];
  float xv[8] = {v0.x,v0.y,v0.z,v0.w,v1.x,v1.y,v1.z,v1.w};
  float gg[8] = {ga.x,ga.y,ga.z,ga.w,gb.x,gb.y,gb.z,gb.w};
  float bv[8] = {ba.x,ba.y,ba.z,ba.w,bb.x,bb.y,bb.z,bb.w};
  union{u16 us[8]; uint4 u;} p;
  #pragma unroll
  for (int j=0;j<8;j++) p.us[j] = f2bf((xv[j]-mean)*rstd*gg[j] + bv[j]);
  ((uint4*)(out + (size_t)r*DIM))[lane] = p.u;
}

// ---------------- bf16 MFMA GEMM (T2 LDS swizzle + T1 XCD swizzle) ----------------
template<int EPI>
__global__ __launch_bounds__(256)
void gemm_kernel(const u16* __restrict__ X, const u16* __restrict__ Wt,
                 const float* __restrict__ bias, u16* __restrict__ obf,
                 float* __restrict__ xres, int M, int N, int K, int shifted)
{
  __shared__ u16 As[128*64];
  __shared__ u16 Bs[128*64];
  int tid = threadIdx.x, wave = tid>>6, lane = tid&63;
  // T1: XCD-aware block swizzle (grid always divisible by 8 here)
  int nwg = gridDim.x * gridDim.y;
  int bid = blockIdx.y * gridDim.x + blockIdx.x;
  int wg  = (bid & 7) * (nwg >> 3) + (bid >> 3);
  int n0 = (wg % gridDim.x) * 128;
  int m0 = (wg / gridDim.x) * 128;
  int wm = (wave>>1)*64, wn = (wave&1)*64;
  f32x4 acc[4][4] = {};
  int srow = tid>>3;
  // T2: pre-swizzled global source chunk; LDS dest stays linear.
  // row&7 == (tid>>3)&7 for all 32-row groups, so the XOR is per-lane constant.
  int soff = (((tid&7) ^ ((tid>>3)&7)))*8;

  for (int k0=0; k0<K; k0+=64){
    __syncthreads();
    #pragma unroll
    for (int i=0;i<4;i++)
      gload16(X + (size_t)(m0 + i*32 + srow)*K + k0 + soff, (void*)(As + (i*256 + wave*64)*8));
    #pragma unroll
    for (int i=0;i<4;i++)
      gload16(Wt + (size_t)(n0 + i*32 + srow)*K + k0 + soff, (void*)(Bs + (i*256 + wave*64)*8));
    __syncthreads();
    #pragma unroll
    for (int kk=0; kk<64; kk+=32){
      short8 af[4], bfr[4];
      #pragma unroll
      for (int mi=0;mi<4;mi++)
        af[mi] = *(const short8*)(As + (wm + mi*16 + (lane&15))*64 + ((kk + (lane>>4)*8) ^ ((lane&7)<<3)));
      #pragma unroll
      for (int nj=0;nj<4;nj++)
        bfr[nj] = *(const short8*)(Bs + (wn + nj*16 + (lane&15))*64 + ((kk + (lane>>4)*8) ^ ((lane&7)<<3)));
      #pragma unroll
      for (int mi=0;mi<4;mi++)
        #pragma unroll
        for (int nj=0;nj<4;nj++)
          acc[mi][nj] = __builtin_amdgcn_mfma_f32_16x16x32_bf16(af[mi], bfr[nj], acc[mi][nj], 0,0,0);
    }
  }

  int lr = (lane>>4)*4, lc = lane&15;
  #pragma unroll
  for (int mi=0;mi<4;mi++){
    #pragma unroll
    for (int nj=0;nj<4;nj++){
      int col = n0 + wn + nj*16 + lc;
      float bv = bias[col];
      #pragma unroll
      for (int rr=0;rr<4;rr++){
        int row = m0 + wm + mi*16 + lr + rr;
        float v = acc[mi][nj][rr] + bv;
        if (EPI==0){
          obf[(size_t)row*N + col] = f2bf(v);
        } else if (EPI==1){
          int dst = win_to_tok(row, shifted);
          xres[(size_t)dst*DIM + col] += v;
        } else if (EPI==2){
          float t = 0.5f*v*(1.f + erff(v*0.70710678118654752f));
          obf[(size_t)row*N + col] = f2bf(t);
        } else {
          xres[(size_t)row*DIM + col] += v;
        }
      }
    }
  }
}

// ---------------- rel-pos bias expansion: biasM[h][q][k] ----------------
__global__ __launch_bounds__(256)
void bias_kernel(const float* __restrict__ btab, float* __restrict__ biasM)
{
  int gid = blockIdx.x*256 + threadIdx.x;   // 16*128*128
  int q = (gid >> 7) & 127, k = gid & 127, h = gid >> 14;
  int ic=q>>6, ih=(q>>3)&7, iw=q&7, jc=k>>6, jh=(k>>3)&7, jw=k&7;
  int idx = (ic-jc+1)*225 + (ih-jh+7)*15 + (iw-jw+7);
  biasM[gid] = btab[idx*16 + h];
}

// ---------------- MFMA windowed attention ----------------
// block = (window, head): 4 waves, wave w owns q-rows [w*32, w*32+32)
__global__ __launch_bounds__(256)
void attn_kernel(const u16* __restrict__ qkv, const float* __restrict__ biasM,
                 u16* __restrict__ out, int shifted)
{
  __shared__ u16 Ks[128*32];    // [krow][d], 16B-chunk ^= (krow&3)<<4
  __shared__ u16 VsT[32*128];   // [d][krow], byte ^= (d&7)<<4
  __shared__ u16 Ps[4][32*128]; // per-wave [q][k], byte ^= (q&7)<<4
  __shared__ int rid[128];
  int win = blockIdx.x >> 4, h = blockIdx.x & 15;
  int tid = threadIdx.x, wave = tid>>6, lane = tid&63;
  size_t base = (size_t)win*128*1536 + (size_t)h*32;

  { // stage K (swizzled) and V transposed (swizzled)
    int m = tid>>1, half = tid&1;
    const uint4* ks = (const uint4*)(qkv + base + (size_t)m*1536 + 512 + half*16);
    uint4 k0v = ks[0], k1v = ks[1];
    char* krow = (char*)Ks + m*64;
    int c0 = half*32, sw = (m&3)<<4;
    *(uint4*)(krow + ((c0     ) ^ sw)) = k0v;
    *(uint4*)(krow + ((c0 + 16) ^ sw)) = k1v;
    const uint4* vs = (const uint4*)(qkv + base + (size_t)m*1536 + 1024 + half*16);
    union{u16 us[16]; uint4 u[2];} vv; vv.u[0]=vs[0]; vv.u[1]=vs[1];
    #pragma unroll
    for (int j=0;j<16;j++){
      int d = half*16 + j;
      *(u16*)((char*)VsT + ((d*256 + m*2) ^ ((d&7)<<4))) = vv.us[j];
    }
  }
  if (shifted && tid < 128){
    int a=win>>6, b=(win>>3)&7, c=win&7;
    int gc=a*2+(tid>>6), gh=b*8+((tid>>3)&7), gw=c*8+(tid&7);
    int rc = (gc<2)?0:((gc<3)?1:2);
    int rh = (gh<56)?0:((gh<60)?1:2);
    int rw = (gw<56)?0:((gw<60)?1:2);
    rid[tid] = rc*9 + rh*3 + rw;
  }
  __syncthreads();

  int q0 = wave*32;
  // ---- QK^T: S[32x128] ----
  short8 qf[2];
  #pragma unroll
  for (int mi=0;mi<2;mi++){
    int ql = 16*mi + (lane&15);
    qf[mi] = *(const short8*)(qkv + base + (size_t)(q0+ql)*1536 + (lane>>4)*8);
  }
  f32x4 s[2][8] = {};
  #pragma unroll
  for (int nj=0;nj<8;nj++){
    int row = (lane&15) + 16*nj;
    short8 kf = *(const short8*)((char*)Ks + row*64 + ((((lane>>4)<<4)) ^ ((row&3)<<4)));
    #pragma unroll
    for (int mi=0;mi<2;mi++)
      s[mi][nj] = __builtin_amdgcn_mfma_f32_16x16x32_bf16(qf[mi], kf, s[mi][nj], 0,0,0);
  }

  // ---- softmax (bias + mask), write P (bf16) to per-wave LDS ----
  int rk[8];
  if (shifted){
    #pragma unroll
    for (int nj=0;nj<8;nj++) rk[nj] = rid[(lane&15) + 16*nj];
  }
  float invl[2][4];
  char* pbase = (char*)Ps[wave];
  #pragma unroll
  for (int mi=0;mi<2;mi++){
    #pragma unroll
    for (int r=0;r<4;r++){
      int ql = 16*mi + ((lane>>4)<<2) + r;
      int qw = q0 + ql;
      const float* bp = biasM + (((h<<7) + qw)<<7) + (lane&15);
      int rq = shifted ? rid[qw] : 0;
      float sv[8]; float mx = -1e30f;
      #pragma unroll
      for (int nj=0;nj<8;nj++){
        float v = s[mi][nj][r] * 0.17677669529663687f + bp[nj*16];
        if (shifted && rk[nj] != rq) v -= 100.f;
        sv[nj] = v; mx = fmaxf(mx, v);
      }
      #pragma unroll
      for (int o=1;o<16;o<<=1) mx = fmaxf(mx, __shfl_xor(mx, o));
      float sum = 0.f;
      #pragma unroll
      for (int nj=0;nj<8;nj++){ float p = __expf(sv[nj]-mx); sv[nj]=p; sum += p; }
      #pragma unroll
      for (int o=1;o<16;o<<=1) sum += __shfl_xor(sum, o);
      invl[mi][r] = 1.f/sum;
      char* prow = pbase + ql*256;
      int sw = (ql&7)<<4;
      #pragma unroll
      for (int nj=0;nj<8;nj++)
        *(u16*)(prow + ((((lane&15) + (nj<<4))<<1) ^ sw)) = f2bf(sv[nj]);
    }
  }

  // ---- PV: O[32x32] ----
  f32x4 o2[2][2] = {};
  #pragma unroll
  for (int kk=0;kk<4;kk++){
    int coff = kk*64 + ((lane>>4)<<4);
    short8 pa[2], vb[2];
    #pragma unroll
    for (int mi=0;mi<2;mi++){
      int ql = 16*mi + (lane&15);
      pa[mi] = *(const short8*)(pbase + ql*256 + (coff ^ ((ql&7)<<4)));
    }
    #pragma unroll
    for (int nj=0;nj<2;nj++){
      int d = (lane&15) + 16*nj;
      vb[nj] = *(const short8*)((char*)VsT + d*256 + (coff ^ ((d&7)<<4)));
    }
    #pragma unroll
    for (int mi=0;mi<2;mi++)
      #pragma unroll
      for (int nj=0;nj<2;nj++)
        o2[mi][nj] = __builtin_amdgcn_mfma_f32_16x16x32_bf16(pa[mi], vb[nj], o2[mi][nj], 0,0,0);
  }

  // ---- epilogue: scale by 1/l, store bf16 ----
  #pragma unroll
  for (int mi=0;mi<2;mi++){
    #pragma unroll
    for (int nj=0;nj<2;nj++){
      #pragma unroll
      for (int r=0;r<4;r++){
        int ql = 16*mi + ((lane>>4)<<2) + r;
        int d  = (lane&15) + (nj<<4);
        out[(size_t)(win*128 + q0 + ql)*DIM + (h<<5) + d] = f2bf(o2[mi][nj][r] * invl[mi][r]);
      }
    }
  }
}

// ---------------- host launcher ----------------
extern "C" void kernel_launch(void* const* d_in, const int* in_sizes, int n_in,
                              void* d_out, int out_size, void* d_ws, size_t ws_size,
                              hipStream_t stream)
{
  const float* x_in   = (const float*)d_in[0];
  const float* ln1_g  = (const float*)d_in[1];
  const float* ln1_b  = (const float*)d_in[2];
  const float* qkv_w  = (const float*)d_in[3];
  const float* qkv_b  = (const float*)d_in[4];
  const float* btab   = (const float*)d_in[5];
  const float* proj_w = (const float*)d_in[6];
  const float* proj_b = (const float*)d_in[7];
  const float* ln2_g  = (const float*)d_in[8];
  const float* ln2_b  = (const float*)d_in[9];
  const float* fc1_w  = (const float*)d_in[10];
  const float* fc1_b  = (const float*)d_in[11];
  const float* fc2_w  = (const float*)d_in[12];
  const float* fc2_b  = (const float*)d_in[13];

  char* ws = (char*)d_ws;
  size_t off = 0;
  auto alloc = [&](size_t bytes)->char*{ char* p = ws + off; off += (bytes + 255) & ~(size_t)255; return p; };
  u16* wT_qkv = (u16*)alloc((size_t)2*512*1536*2);
  u16* wT_proj= (u16*)alloc((size_t)2*512*512*2);
  u16* wT_fc1 = (u16*)alloc((size_t)2*2048*512*2);
  u16* wT_fc2 = (u16*)alloc((size_t)2*512*2048*2);
  u16* bufA   = (u16*)alloc((size_t)16384*2048*2);
  u16* bufQ   = (u16*)alloc((size_t)16384*1536*2);
  u16* bufB   = (u16*)alloc((size_t)16384*512*2);
  float* biasM= (float*)alloc((size_t)16*128*128*4);
  (void)ws_size; (void)in_sizes; (void)n_in; (void)out_size;

  float* x = (float*)d_out;
  hipMemcpyAsync(x, x_in, (size_t)NTOK*DIM*4, hipMemcpyDeviceToDevice, stream);

  for (int i=0;i<2;i++){
    transpose_kernel<<<dim3(1536/32, 512/32), 256, 0, stream>>>(qkv_w + (size_t)i*512*1536, wT_qkv + (size_t)i*512*1536, 512, 1536);
    transpose_kernel<<<dim3( 512/32, 512/32), 256, 0, stream>>>(proj_w + (size_t)i*512*512,  wT_proj + (size_t)i*512*512,  512, 512);
    transpose_kernel<<<dim3(2048/32, 512/32), 256, 0, stream>>>(fc1_w + (size_t)i*512*2048, wT_fc1 + (size_t)i*2048*512, 512, 2048);
    transpose_kernel<<<dim3( 512/32,2048/32), 256, 0, stream>>>(fc2_w + (size_t)i*2048*512, wT_fc2 + (size_t)i*512*2048, 2048, 512);
  }

  for (int i=0;i<2;i++){
    ln_kernel<<<4096, 256, 0, stream>>>(x, ln1_g+i*512, ln1_b+i*512, bufA, i);
    gemm_kernel<0><<<dim3(12,128), 256, 0, stream>>>(bufA, wT_qkv+(size_t)i*512*1536, qkv_b+i*1536, bufQ, nullptr, NTOK,1536,512, 0);
    bias_kernel<<<1024, 256, 0, stream>>>(btab + (size_t)i*675*16, biasM);
    attn_kernel<<<2048, 256, 0, stream>>>(bufQ, biasM, bufB, i);
    gemm_kernel<1><<<dim3(4,128), 256, 0, stream>>>(bufB, wT_proj+(size_t)i*512*512, proj_b+i*512, nullptr, x, NTOK,512,512, i);
    ln_kernel<<<4096, 256, 0, stream>>>(x, ln2_g+i*512, ln2_b+i*512, bufB, -1);
    gemm_kernel<2><<<dim3(16,128), 256, 0, stream>>>(bufB, wT_fc1+(size_t)i*2048*512, fc1_b+i*2048, bufA, nullptr, NTOK,2048,512, 0);
    gemm_kernel<3><<<dim3(4,128), 256, 0, stream>>>(bufA, wT_fc2+(size_t)i*512*2048, fc2_b+i*512, nullptr, x, NTOK,512,2048, 0);
  }
}

// Round 5
// 435.799 us; speedup vs baseline: 1.7565x; 1.0587x over previous
//
#include <hip/hip_runtime.h>
#include <stdint.h>

#define DIM 512
#define NHD 16
#define HD 32
#define NTOK 16384

typedef unsigned short u16;
typedef __attribute__((ext_vector_type(8))) short short8;  // 8 bf16 (4 VGPRs)
typedef __attribute__((ext_vector_type(4))) float f32x4;

__device__ __forceinline__ float bf2f(u16 u){ union{unsigned i; float f;} c; c.i=(unsigned)u<<16; return c.f; }
__device__ __forceinline__ float bflo(unsigned u){ union{unsigned i; float f;} c; c.i=u<<16; return c.f; }
__device__ __forceinline__ float bfhi(unsigned u){ union{unsigned i; float f;} c; c.i=u&0xffff0000u; return c.f; }
__device__ __forceinline__ u16 f2bf(float f){ union{float f; unsigned i;} c; c.f=f; unsigned r=(c.i + 0x7fffu + ((c.i>>16)&1u))>>16; return (u16)r; }

// window-order row -> token index (with optional shift roll-back/gather mapping)
__device__ __forceinline__ int win_to_tok(int r, int shifted){
  int win = r >> 7, n = r & 127;
  int a = win >> 6, b = (win >> 3) & 7, c = win & 7;
  int ic = n >> 6, ih = (n >> 3) & 7, iw = n & 7;
  int gc = a*2 + ic, gh = b*8 + ih, gw = c*8 + iw;
  if (shifted){ gc = (gc + 1) & 3; gh = (gh + 4) & 63; gw = (gw + 4) & 63; }
  return (gc << 12) + (gh << 6) + gw;
}

__device__ __forceinline__ void gload16(const void* g, void* l){
  __builtin_amdgcn_global_load_lds(
    (const __attribute__((address_space(1))) unsigned int*)(unsigned long long)g,
    (__attribute__((address_space(3))) unsigned int*)(unsigned int)(unsigned long long)l,
    16, 0, 0);
}

// ---------------- weight transpose + bf16 cast ----------------
__global__ __launch_bounds__(256)
void transpose_kernel(const float* __restrict__ W, u16* __restrict__ Wt, int K, int N)
{
  __shared__ float t[32][33];
  int n0 = blockIdx.x*32, k0 = blockIdx.y*32;
  int tx = threadIdx.x & 31, ty = threadIdx.x >> 5;
  #pragma unroll
  for (int i=0;i<4;i++) t[ty + i*8][tx] = W[(size_t)(k0 + ty + i*8)*N + n0 + tx];
  __syncthreads();
  #pragma unroll
  for (int i=0;i<4;i++) Wt[(size_t)(n0 + ty + i*8)*K + k0 + tx] = f2bf(t[tx][ty + i*8]);
}

// ---------------- LayerNorm (+optional window gather w/ roll) -> bf16 ----------------
__global__ __launch_bounds__(256)
void ln_kernel(const float* __restrict__ x, const float* __restrict__ g,
               const float* __restrict__ b, u16* __restrict__ out, int mode)
{
  int wave = threadIdx.x >> 6, lane = threadIdx.x & 63;
  int r = blockIdx.x * 4 + wave;
  int src = (mode < 0) ? r : win_to_tok(r, mode);
  const float4* xr = (const float4*)(x + (size_t)src * DIM);
  float4 v0 = xr[lane*2], v1 = xr[lane*2+1];
  float s  = v0.x+v0.y+v0.z+v0.w+v1.x+v1.y+v1.z+v1.w;
  float sq = v0.x*v0.x+v0.y*v0.y+v0.z*v0.z+v0.w*v0.w
           + v1.x*v1.x+v1.y*v1.y+v1.z*v1.z+v1.w*v1.w;
  #pragma unroll
  for (int o=32;o;o>>=1){ s += __shfl_xor(s,o); sq += __shfl_xor(sq,o); }
  float mean = s*(1.f/DIM);
  float var  = sq*(1.f/DIM) - mean*mean;
  float rstd = rsqrtf(var + 1e-5f);
  int c0 = lane*8;
  const float4* g4 = (const float4*)(g + c0);
  const float4* b4 = (const float4*)(b + c0);
  float4 ga = g4[0], gb = g4[1], ba = b4[0], bb = b4[1];
  float xv[8] = {v0.x,v0.y,v0.z,v0.w,v1.x,v1.y,v1.z,v1.w};
  float gg[8] = {ga.x,ga.y,ga.z,ga.w,gb.x,gb.y,gb.z,gb.w};
  float bv[8] = {ba.x,ba.y,ba.z,ba.w,bb.x,bb.y,bb.z,bb.w};
  union{u16 us[8]; uint4 u;} p;
  #pragma unroll
  for (int j=0;j<8;j++) p.us[j] = f2bf((xv[j]-mean)*rstd*gg[j] + bv[j]);
  ((uint4*)(out + (size_t)r*DIM))[lane] = p.u;
}

// ---------------- bf16 MFMA GEMM: 128x128 tile, 2-phase dbuf, LDS-repacked epilogue ----------------
// EPI 0: store bf16 (qkv)   EPI 1: scatter += into x residual (proj, win_rev+roll)
// EPI 2: tanh-gelu -> bf16 (fc1) EPI 3: += into x residual direct (fc2)
template<int EPI>
__global__ __launch_bounds__(256)
void gemm_kernel(const u16* __restrict__ X, const u16* __restrict__ Wt,
                 const float* __restrict__ bias, u16* __restrict__ obf,
                 float* __restrict__ xres, int M, int N, int K, int shifted)
{
  __shared__ u16 smem[4][128*64];   // [0..1]=A dbuf, [2..3]=B dbuf; epilogue reuses all 64 KB
  int tid = threadIdx.x, wave = tid>>6, lane = tid&63;
  // T1: XCD-aware block swizzle (grid always divisible by 8 here)
  int nwg = gridDim.x * gridDim.y;
  int bid = blockIdx.y * gridDim.x + blockIdx.x;
  int wg  = (bid & 7) * (nwg >> 3) + (bid >> 3);
  int n0 = (wg % gridDim.x) * 128;
  int m0 = (wg / gridDim.x) * 128;
  int wm = (wave>>1)*64, wn = (wave&1)*64;
  f32x4 acc[4][4] = {};
  int srow = tid>>3;
  // T2: pre-swizzled global source chunk; LDS dest stays linear.
  int soff = (((tid&7) ^ ((tid>>3)&7)))*8;

  auto stage = [&](int c, int k0){
    #pragma unroll
    for (int i=0;i<4;i++)
      gload16(X + (size_t)(m0 + i*32 + srow)*K + k0 + soff, (void*)(smem[c] + i*2048 + wave*512));
    #pragma unroll
    for (int i=0;i<4;i++)
      gload16(Wt + (size_t)(n0 + i*32 + srow)*K + k0 + soff, (void*)(smem[2+c] + i*2048 + wave*512));
  };

  stage(0, 0);
  __syncthreads();                       // implicit vmcnt(0) drain: buf0 ready
  int nkt = K >> 6;
  for (int kt=0; kt<nkt; ++kt){
    int c = kt & 1;
    if (kt+1 < nkt) stage(c^1, (kt+1)<<6);   // issue next tile BEFORE compute
    const u16* Ab = smem[c];
    const u16* Bb = smem[2+c];
    #pragma unroll
    for (int kk=0; kk<64; kk+=32){
      short8 af[4], bfr[4];
      int cofs = (kk + (lane>>4)*8) ^ ((lane&7)<<3);
      #pragma unroll
      for (int mi=0;mi<4;mi++)
        af[mi] = *(const short8*)(Ab + (wm + mi*16 + (lane&15))*64 + cofs);
      #pragma unroll
      for (int nj=0;nj<4;nj++)
        bfr[nj] = *(const short8*)(Bb + (wn + nj*16 + (lane&15))*64 + cofs);
      __builtin_amdgcn_s_setprio(1);
      #pragma unroll
      for (int mi=0;mi<4;mi++)
        #pragma unroll
        for (int nj=0;nj<4;nj++)
          acc[mi][nj] = __builtin_amdgcn_mfma_f32_16x16x32_bf16(af[mi], bfr[nj], acc[mi][nj], 0,0,0);
      __builtin_amdgcn_s_setprio(0);
    }
    __syncthreads();                     // drain: next buf staged, reads of c done
  }

  // ---- epilogue: values -> LDS repack (swizzled) -> coalesced global ----
  int lr = (lane>>4)*4, lc = lane&15;
  if (EPI==0 || EPI==2){
    u16* et = (u16*)smem;                // logical [128][128] bf16, byte ^= ((row>>2)&3)<<5
    #pragma unroll
    for (int mi=0;mi<4;mi++){
      #pragma unroll
      for (int nj=0;nj<4;nj++){
        int col = wn + nj*16 + lc;
        float bv = bias[n0 + col];
        #pragma unroll
        for (int rr=0;rr<4;rr++){
          int row = wm + mi*16 + lr + rr;
          float v = acc[mi][nj][rr] + bv;
          if (EPI==2){
            float u2 = v*(1.5957691216057308f + 0.0713548162726f*v*v); // 2*0.79788456*(v + 0.044715 v^3)
            v = v * __builtin_amdgcn_rcpf(1.f + __expf(-u2));          // v * sigmoid(2w) = tanh-GELU
          }
          *(u16*)((char*)et + ((row*256 + col*2) ^ (((row>>2)&3)<<5))) = f2bf(v);
        }
      }
    }
    __syncthreads();
    #pragma unroll
    for (int j=0;j<8;j++){
      int q = j*256 + tid;               // 2048 16B-chunks
      int row = q>>4, cc = q&15;
      uint4 d = *(const uint4*)((char*)et + ((row*256 + cc*16) ^ (((row>>2)&3)<<5)));
      *(uint4*)(obf + (size_t)(m0+row)*N + n0 + cc*8) = d;
    }
  } else {
    float* et = (float*)smem;            // logical [128][128] f32, byte ^= ((row>>2)&1)<<6
    #pragma unroll
    for (int mi=0;mi<4;mi++){
      #pragma unroll
      for (int nj=0;nj<4;nj++){
        int col = wn + nj*16 + lc;
        float bv = bias[n0 + col];
        #pragma unroll
        for (int rr=0;rr<4;rr++){
          int row = wm + mi*16 + lr + rr;
          *(float*)((char*)et + ((row*512 + col*4) ^ (((row>>2)&1)<<6))) = acc[mi][nj][rr] + bv;
        }
      }
    }
    __syncthreads();
    #pragma unroll
    for (int j=0;j<16;j++){
      int q = j*256 + tid;               // 4096 16B-chunks
      int row = q>>5, cc = q&31;
      float4 d = *(const float4*)((char*)et + ((row*512 + cc*16) ^ (((row>>2)&1)<<6)));
      int grow = (EPI==1) ? win_to_tok(m0+row, shifted) : (m0+row);
      float4* p = (float4*)(xres + (size_t)grow*DIM + n0 + cc*4);
      float4 o = *p;
      o.x += d.x; o.y += d.y; o.z += d.z; o.w += d.w;
      *p = o;
    }
  }
}

// ---------------- rel-pos bias expansion: biasM[h][q][k] ----------------
__global__ __launch_bounds__(256)
void bias_kernel(const float* __restrict__ btab, float* __restrict__ biasM)
{
  int gid = blockIdx.x*256 + threadIdx.x;   // 16*128*128
  int q = (gid >> 7) & 127, k = gid & 127, h = gid >> 14;
  int ic=q>>6, ih=(q>>3)&7, iw=q&7, jc=k>>6, jh=(k>>3)&7, jw=k&7;
  int idx = (ic-jc+1)*225 + (ih-jh+7)*15 + (iw-jw+7);
  biasM[gid] = btab[idx*16 + h];
}

// ---------------- MFMA windowed attention ----------------
// block = (window, head): 4 waves, wave w owns q-rows [w*32, w*32+32)
__global__ __launch_bounds__(256)
void attn_kernel(const u16* __restrict__ qkv, const float* __restrict__ biasM,
                 u16* __restrict__ out, int shifted)
{
  __shared__ u16 Ks[128*32];    // [krow][d], 16B-chunk ^= (krow&3)<<4
  __shared__ u16 VsT[32*128];   // [d][krow], byte ^= (d&7)<<4
  __shared__ u16 Ps[4][32*128]; // per-wave [q][k], byte ^= (q&7)<<4
  __shared__ int rid[128];
  int win = blockIdx.x >> 4, h = blockIdx.x & 15;
  int tid = threadIdx.x, wave = tid>>6, lane = tid&63;
  size_t base = (size_t)win*128*1536 + (size_t)h*32;

  { // stage K (swizzled) and V transposed (swizzled)
    int m = tid>>1, half = tid&1;
    const uint4* ks = (const uint4*)(qkv + base + (size_t)m*1536 + 512 + half*16);
    uint4 k0v = ks[0], k1v = ks[1];
    char* krow = (char*)Ks + m*64;
    int c0 = half*32, sw = (m&3)<<4;
    *(uint4*)(krow + ((c0     ) ^ sw)) = k0v;
    *(uint4*)(krow + ((c0 + 16) ^ sw)) = k1v;
    const uint4* vs = (const uint4*)(qkv + base + (size_t)m*1536 + 1024 + half*16);
    union{u16 us[16]; uint4 u[2];} vv; vv.u[0]=vs[0]; vv.u[1]=vs[1];
    #pragma unroll
    for (int j=0;j<16;j++){
      int d = half*16 + j;
      *(u16*)((char*)VsT + ((d*256 + m*2) ^ ((d&7)<<4))) = vv.us[j];
    }
  }
  if (shifted && tid < 128){
    int a=win>>6, b=(win>>3)&7, c=win&7;
    int gc=a*2+(tid>>6), gh=b*8+((tid>>3)&7), gw=c*8+(tid&7);
    int rc = (gc<2)?0:((gc<3)?1:2);
    int rh = (gh<56)?0:((gh<60)?1:2);
    int rw = (gw<56)?0:((gw<60)?1:2);
    rid[tid] = rc*9 + rh*3 + rw;
  }
  __syncthreads();

  int q0 = wave*32;
  // ---- QK^T: S[32x128] ----
  short8 qf[2];
  #pragma unroll
  for (int mi=0;mi<2;mi++){
    int ql = 16*mi + (lane&15);
    qf[mi] = *(const short8*)(qkv + base + (size_t)(q0+ql)*1536 + (lane>>4)*8);
  }
  f32x4 s[2][8] = {};
  #pragma unroll
  for (int nj=0;nj<8;nj++){
    int row = (lane&15) + 16*nj;
    short8 kf = *(const short8*)((char*)Ks + row*64 + ((((lane>>4)<<4)) ^ ((row&3)<<4)));
    #pragma unroll
    for (int mi=0;mi<2;mi++)
      s[mi][nj] = __builtin_amdgcn_mfma_f32_16x16x32_bf16(qf[mi], kf, s[mi][nj], 0,0,0);
  }

  // ---- softmax (bias + mask), write P (bf16) to per-wave LDS ----
  int rk[8];
  if (shifted){
    #pragma unroll
    for (int nj=0;nj<8;nj++) rk[nj] = rid[(lane&15) + 16*nj];
  }
  float invl[2][4];
  char* pbase = (char*)Ps[wave];
  #pragma unroll
  for (int mi=0;mi<2;mi++){
    #pragma unroll
    for (int r=0;r<4;r++){
      int ql = 16*mi + ((lane>>4)<<2) + r;
      int qw = q0 + ql;
      const float* bp = biasM + (((h<<7) + qw)<<7) + (lane&15);
      int rq = shifted ? rid[qw] : 0;
      float sv[8]; float mx = -1e30f;
      #pragma unroll
      for (int nj=0;nj<8;nj++){
        float v = s[mi][nj][r] * 0.17677669529663687f + bp[nj*16];
        if (shifted && rk[nj] != rq) v -= 100.f;
        sv[nj] = v; mx = fmaxf(mx, v);
      }
      #pragma unroll
      for (int o=1;o<16;o<<=1) mx = fmaxf(mx, __shfl_xor(mx, o));
      float sum = 0.f;
      #pragma unroll
      for (int nj=0;nj<8;nj++){ float p = __expf(sv[nj]-mx); sv[nj]=p; sum += p; }
      #pragma unroll
      for (int o=1;o<16;o<<=1) sum += __shfl_xor(sum, o);
      invl[mi][r] = 1.f/sum;
      char* prow = pbase + ql*256;
      int sw = (ql&7)<<4;
      #pragma unroll
      for (int nj=0;nj<8;nj++)
        *(u16*)(prow + ((((lane&15) + (nj<<4))<<1) ^ sw)) = f2bf(sv[nj]);
    }
  }

  // ---- PV: O[32x32] ----
  f32x4 o2[2][2] = {};
  #pragma unroll
  for (int kk=0;kk<4;kk++){
    int coff = kk*64 + ((lane>>4)<<4);
    short8 pa[2], vb[2];
    #pragma unroll
    for (int mi=0;mi<2;mi++){
      int ql = 16*mi + (lane&15);
      pa[mi] = *(const short8*)(pbase + ql*256 + (coff ^ ((ql&7)<<4)));
    }
    #pragma unroll
    for (int nj=0;nj<2;nj++){
      int d = (lane&15) + 16*nj;
      vb[nj] = *(const short8*)((char*)VsT + d*256 + (coff ^ ((d&7)<<4)));
    }
    #pragma unroll
    for (int mi=0;mi<2;mi++)
      #pragma unroll
      for (int nj=0;nj<2;nj++)
        o2[mi][nj] = __builtin_amdgcn_mfma_f32_16x16x32_bf16(pa[mi], vb[nj], o2[mi][nj], 0,0,0);
  }

  // ---- epilogue: scale by 1/l, store bf16 ----
  #pragma unroll
  for (int mi=0;mi<2;mi++){
    #pragma unroll
    for (int nj=0;nj<2;nj++){
      #pragma unroll
      for (int r=0;r<4;r++){
        int ql = 16*mi + ((lane>>4)<<2) + r;
        int d  = (lane&15) + (nj<<4);
        out[(size_t)(win*128 + q0 + ql)*DIM + (h<<5) + d] = f2bf(o2[mi][nj][r] * invl[mi][r]);
      }
    }
  }
}

// ---------------- host launcher ----------------
extern "C" void kernel_launch(void* const* d_in, const int* in_sizes, int n_in,
                              void* d_out, int out_size, void* d_ws, size_t ws_size,
                              hipStream_t stream)
{
  const float* x_in   = (const float*)d_in[0];
  const float* ln1_g  = (const float*)d_in[1];
  const float* ln1_b  = (const float*)d_in[2];
  const float* qkv_w  = (const float*)d_in[3];
  const float* qkv_b  = (const float*)d_in[4];
  const float* btab   = (const float*)d_in[5];
  const float* proj_w = (const float*)d_in[6];
  const float* proj_b = (const float*)d_in[7];
  const float* ln2_g  = (const float*)d_in[8];
  const float* ln2_b  = (const float*)d_in[9];
  const float* fc1_w  = (const float*)d_in[10];
  const float* fc1_b  = (const float*)d_in[11];
  const float* fc2_w  = (const float*)d_in[12];
  const float* fc2_b  = (const float*)d_in[13];

  char* ws = (char*)d_ws;
  size_t off = 0;
  auto alloc = [&](size_t bytes)->char*{ char* p = ws + off; off += (bytes + 255) & ~(size_t)255; return p; };
  u16* wT_qkv = (u16*)alloc((size_t)2*512*1536*2);
  u16* wT_proj= (u16*)alloc((size_t)2*512*512*2);
  u16* wT_fc1 = (u16*)alloc((size_t)2*2048*512*2);
  u16* wT_fc2 = (u16*)alloc((size_t)2*512*2048*2);
  u16* bufA   = (u16*)alloc((size_t)16384*2048*2);
  u16* bufQ   = (u16*)alloc((size_t)16384*1536*2);
  u16* bufB   = (u16*)alloc((size_t)16384*512*2);
  float* biasM= (float*)alloc((size_t)16*128*128*4);
  (void)ws_size; (void)in_sizes; (void)n_in; (void)out_size;

  float* x = (float*)d_out;
  hipMemcpyAsync(x, x_in, (size_t)NTOK*DIM*4, hipMemcpyDeviceToDevice, stream);

  for (int i=0;i<2;i++){
    transpose_kernel<<<dim3(1536/32, 512/32), 256, 0, stream>>>(qkv_w + (size_t)i*512*1536, wT_qkv + (size_t)i*512*1536, 512, 1536);
    transpose_kernel<<<dim3( 512/32, 512/32), 256, 0, stream>>>(proj_w + (size_t)i*512*512,  wT_proj + (size_t)i*512*512,  512, 512);
    transpose_kernel<<<dim3(2048/32, 512/32), 256, 0, stream>>>(fc1_w + (size_t)i*512*2048, wT_fc1 + (size_t)i*2048*512, 512, 2048);
    transpose_kernel<<<dim3( 512/32,2048/32), 256, 0, stream>>>(fc2_w + (size_t)i*2048*512, wT_fc2 + (size_t)i*512*2048, 2048, 512);
  }

  for (int i=0;i<2;i++){
    ln_kernel<<<4096, 256, 0, stream>>>(x, ln1_g+i*512, ln1_b+i*512, bufA, i);
    gemm_kernel<0><<<dim3(12,128), 256, 0, stream>>>(bufA, wT_qkv+(size_t)i*512*1536, qkv_b+i*1536, bufQ, nullptr, NTOK,1536,512, 0);
    bias_kernel<<<1024, 256, 0, stream>>>(btab + (size_t)i*675*16, biasM);
    attn_kernel<<<2048, 256, 0, stream>>>(bufQ, biasM, bufB, i);
    gemm_kernel<1><<<dim3(4,128), 256, 0, stream>>>(bufB, wT_proj+(size_t)i*512*512, proj_b+i*512, nullptr, x, NTOK,512,512, i);
    ln_kernel<<<4096, 256, 0, stream>>>(x, ln2_g+i*512, ln2_b+i*512, bufB, -1);
    gemm_kernel<2><<<dim3(16,128), 256, 0, stream>>>(bufB, wT_fc1+(size_t)i*2048*512, fc1_b+i*2048, bufA, nullptr, NTOK,2048,512, 0);
    gemm_kernel<3><<<dim3(4,128), 256, 0, stream>>>(bufA, wT_fc2+(size_t)i*512*2048, fc2_b+i*512, nullptr, x, NTOK,512,2048, 0);
  }
}